// Round 10
// baseline (602.220 us; speedup 1.0000x reference)
//
#include <hip/hip_runtime.h>
#include <math.h>
#include <stdint.h>

namespace {

constexpr int EP = 200;

// ======================================================================
// numpy loops_trigonometric.dispatch f32 sin/cos — fused single-reduction
// emulation. Bit-identical to separate sin/cos (verified R8).
// ======================================================================

__device__ __forceinline__ void np_sincosf(float x, float* sp, float* cp) {
#pragma clang fp contract(off)
    const float two_over_pi = 0x1.45f306p-1f;
    const float rint_cvt    = 0x1.8p+23f;
    const float cw_hi  = -0x1.921fb0p+0f;
    const float cw_med = -0x1.5110b4p-22f;
    const float cw_lo  = -0x1.846988p-48f;

    float qf = x * two_over_pi;
    qf = (qf + rint_cvt) - rint_cvt;
    int iq = (int)qf;

    float r = fmaf(qf, cw_hi,  x);
    r = fmaf(qf, cw_med, r);
    r = fmaf(qf, cw_lo,  r);
    float r2 = r * r;

    float ps = fmaf(0x1.5d866ap-19f, r2, -0x1.9f0836p-13f);
    ps = fmaf(ps, r2,  0x1.11119ap-7f);
    ps = fmaf(ps, r2, -0x1.555548p-3f);
    float sinp = fmaf(ps * r2, r, r);

    float pc = fmaf(0x1.98e616p-16f, r2, -0x1.6c06dcp-10f);
    pc = fmaf(pc, r2,  0x1.55553cp-5f);
    pc = fmaf(pc, r2, -0.5f);
    float cosp = fmaf(pc, r2,  1.0f);

    int iqc = iq + 1;
    float s = ((iq  & 1) == 0) ? sinp : cosp;
    float c = ((iqc & 1) == 0) ? sinp : cosp;
    s = (iq  & 2) ? -s : s;
    c = (iqc & 2) ? -c : c;
    *sp = s; *cp = c;
}

// CR f32 atan2 via f64 atan2 + single rounding (verified R7/R8/R9 pass).
__device__ __forceinline__ float cr_atan2f(float y, float x) {
    return (float)atan2((double)y, (double)x);
}

__device__ __forceinline__ float clipf(float x, float lo, float hi) {
    return fminf(fmaxf(x, lo), hi);
}

struct V3 { float a, b, c; };

__device__ __forceinline__ V3 dyn(float y0, float y1, float y2, float u, float dtv) {
#pragma clang fp contract(off)
    const float PI_F = (float)3.141592653589793;
    const float TP_F = (float)6.283185307179586;   // == 2*PI_F exactly
    float th = cr_atan2f(y1, y0);
    float w = th + PI_F;
    float r = (w < TP_F) ? w : 0.0f;               // == numpy mod(w, 2pi) here
    th = r - PI_F;
    float acc = 15.0f * y1 + 3.0f * u;
    float nd  = clipf(y2 + acc * dtv, -8.0f, 8.0f);
    float nth = th + nd * dtv;
    float s, c;
    np_sincosf(nth, &s, &c);
    return V3{ -s * nd, c * nd, acc };
}

// Per-trajectory rolling state
struct Traj {
    const float* tb;
    const float* ab;
    float* orow;
    float y0, y1, y2;
    float t0, t1, a1, u0;
};

__device__ __forceinline__ void traj_init(Traj& T, const float* ob, const float* acs,
                                          const float* times, float* out, int b) {
    T.tb = times + (size_t)b * EP;
    T.ab = acs   + (size_t)b * EP;
    T.orow = out + (size_t)b * EP * 3;
    T.y0 = ob[b * 3 + 0]; T.y1 = ob[b * 3 + 1]; T.y2 = ob[b * 3 + 2];
    T.orow[0] = T.y0; T.orow[1] = T.y1; T.orow[2] = T.y2;
    T.t0 = T.tb[0];
    T.t1 = T.tb[1];
    T.a1 = T.ab[1];
    T.u0 = clipf(T.ab[0], -2.0f, 2.0f);
}

// One full DOPRI5 step for one trajectory; branchless (single basic block
// after inlining) so two calls interleave in the scheduler.
__device__ __forceinline__ void traj_step(Traj& T, int i) {
#pragma clang fp contract(off)
    const float c21 = (float)(1.0/5.0);
    const float c31 = (float)(3.0/40.0),      c32 = (float)(9.0/40.0);
    const float c41 = (float)(44.0/45.0),     c42 = (float)(56.0/15.0),    c43 = (float)(32.0/9.0);
    const float c51 = (float)(19372.0/6561.0),c52 = (float)(25360.0/2187.0),
                c53 = (float)(64448.0/6561.0),c54 = (float)(212.0/729.0);
    const float c61 = (float)(9017.0/3168.0), c62 = (float)(355.0/33.0),
                c63 = (float)(46732.0/5247.0),c64 = (float)(49.0/176.0),   c65 = (float)(5103.0/18656.0);
    const float b1  = (float)(35.0/384.0),    b3  = (float)(500.0/1113.0),
                b4  = (float)(125.0/192.0),   b5  = (float)(2187.0/6784.0),b6  = (float)(11.0/84.0);

    int i2 = (i + 2 < EP) ? (i + 2) : (EP - 1);
    float t2 = T.tb[i2];
    float a2 = T.ab[i2];

    float h   = T.t1 - T.t0;
    float u1c = clipf(T.a1, -2.0f, 2.0f);

    float t6 = T.t0 + h;
    bool ge = (t6 >= T.t1);                  // searchsorted(side=right)-1 == i+1 ?
    float u6  = ge ? u1c : T.u0;
    float dt6 = ge ? (t2 - T.t1) : h;

    float y0 = T.y0, y1v = T.y1, y2 = T.y2, u0 = T.u0;

    V3 k1 = dyn(y0, y1v, y2, u0, h);

    float ta = c21 * k1.a, tb_ = c21 * k1.b, tc = c21 * k1.c;
    V3 k2 = dyn(y0 + h * ta, y1v + h * tb_, y2 + h * tc, u0, h);

    float a3  = c31 * k1.a + c32 * k2.a;
    float b3_ = c31 * k1.b + c32 * k2.b;
    float cc3 = c31 * k1.c + c32 * k2.c;
    V3 k3 = dyn(y0 + h * a3, y1v + h * b3_, y2 + h * cc3, u0, h);

    float a4  = c41 * k1.a - c42 * k2.a + c43 * k3.a;
    float b4_ = c41 * k1.b - c42 * k2.b + c43 * k3.b;
    float cc4 = c41 * k1.c - c42 * k2.c + c43 * k3.c;
    V3 k4 = dyn(y0 + h * a4, y1v + h * b4_, y2 + h * cc4, u0, h);

    float a5  = c51 * k1.a - c52 * k2.a + c53 * k3.a - c54 * k4.a;
    float b5_ = c51 * k1.b - c52 * k2.b + c53 * k3.b - c54 * k4.b;
    float cc5 = c51 * k1.c - c52 * k2.c + c53 * k3.c - c54 * k4.c;
    V3 k5 = dyn(y0 + h * a5, y1v + h * b5_, y2 + h * cc5, u0, h);

    float a6  = c61 * k1.a - c62 * k2.a + c63 * k3.a + c64 * k4.a - c65 * k5.a;
    float b6_ = c61 * k1.b - c62 * k2.b + c63 * k3.b + c64 * k4.b - c65 * k5.b;
    float cc6 = c61 * k1.c - c62 * k2.c + c63 * k3.c + c64 * k4.c - c65 * k5.c;
    V3 k6 = dyn(y0 + h * a6, y1v + h * b6_, y2 + h * cc6, u6, dt6);

    float ua = b1 * k1.a + b3 * k3.a + b4 * k4.a - b5 * k5.a + b6 * k6.a;
    float ub = b1 * k1.b + b3 * k3.b + b4 * k4.b - b5 * k5.b + b6 * k6.b;
    float uc = b1 * k1.c + b3 * k3.c + b4 * k4.c - b5 * k5.c + b6 * k6.c;
    T.y0 = y0  + h * ua;
    T.y1 = y1v + h * ub;
    T.y2 = y2  + h * uc;

    float* rr = T.orow + (size_t)(i + 1) * 3;
    rr[0] = T.y0; rr[1] = T.y1; rr[2] = T.y2;

    T.t0 = T.t1; T.t1 = t2;
    T.a1 = a2;
    T.u0 = u1c;
}

// Two independent trajectories per thread: the second chain's instructions
// fill the first chain's dependency-stall gaps (one wave per SIMD otherwise
// has nothing to issue during the f64 atan2 latency).
__global__ __launch_bounds__(64, 1) void pend_rollout2(
        const float* __restrict__ ob,
        const float* __restrict__ acs,
        const float* __restrict__ times,
        float* __restrict__ out, int B, int B2) {
#pragma clang fp contract(off)
    int t = blockIdx.x * blockDim.x + threadIdx.x;
    if (t >= B2) return;
    int p = t;
    int q = t + B2;
    bool hasQ = (q < B);

    Traj A, Bt;
    traj_init(A, ob, acs, times, out, p);
    if (hasQ) traj_init(Bt, ob, acs, times, out, q);

    if (hasQ) {
        for (int i = 0; i < EP - 1; ++i) {
            traj_step(A, i);
            traj_step(Bt, i);
        }
    } else {
        for (int i = 0; i < EP - 1; ++i) traj_step(A, i);
    }
}

} // namespace

extern "C" void kernel_launch(void* const* d_in, const int* in_sizes, int n_in,
                              void* d_out, int out_size, void* d_ws, size_t ws_size,
                              hipStream_t stream) {
    const float* ob    = (const float*)d_in[0];
    const float* acs   = (const float*)d_in[1];
    const float* times = (const float*)d_in[2];
    float* out = (float*)d_out;
    int B = in_sizes[0] / 3;
    int B2 = (B + 1) / 2;

    int block = 64;
    int grid = (B2 + block - 1) / block;
    pend_rollout2<<<grid, block, 0, stream>>>(ob, acs, times, out, B, B2);
}

// Round 11
// 353.651 us; speedup vs baseline: 1.7029x; 1.7029x over previous
//
#include <hip/hip_runtime.h>
#include <math.h>
#include <stdint.h>

namespace {

constexpr int EP = 200;

// ======================================================================
// numpy loops_trigonometric.dispatch f32 sin/cos — fused single-reduction
// emulation. Bit-identical to separate sin/cos calls (verified R8).
// ======================================================================

__device__ __forceinline__ void np_sincosf(float x, float* sp, float* cp) {
#pragma clang fp contract(off)
    const float two_over_pi = 0x1.45f306p-1f;
    const float rint_cvt    = 0x1.8p+23f;
    const float cw_hi  = -0x1.921fb0p+0f;
    const float cw_med = -0x1.5110b4p-22f;
    const float cw_lo  = -0x1.846988p-48f;

    float qf = x * two_over_pi;
    qf = (qf + rint_cvt) - rint_cvt;          // rint via round-trip
    int iq = (int)qf;                          // sin quadrant; cos = iq+1

    float r = fmaf(qf, cw_hi,  x);
    r = fmaf(qf, cw_med, r);
    r = fmaf(qf, cw_lo,  r);
    float r2 = r * r;

    // sine poly: x + x^3*P(x^2) via fma chain (identical op order)
    float ps = fmaf(0x1.5d866ap-19f, r2, -0x1.9f0836p-13f);
    ps = fmaf(ps, r2,  0x1.11119ap-7f);
    ps = fmaf(ps, r2, -0x1.555548p-3f);
    float sinp = fmaf(ps * r2, r, r);

    // cosine poly: Horner in x^2 (identical op order)
    float pc = fmaf(0x1.98e616p-16f, r2, -0x1.6c06dcp-10f);
    pc = fmaf(pc, r2,  0x1.55553cp-5f);
    pc = fmaf(pc, r2, -0.5f);
    float cosp = fmaf(pc, r2,  1.0f);

    int iqc = iq + 1;
    float s = ((iq  & 1) == 0) ? sinp : cosp;
    float c = ((iqc & 1) == 0) ? sinp : cosp;
    s = (iq  & 2) ? -s : s;
    c = (iqc & 2) ? -c : c;
    *sp = s; *cp = c;
}

// CR f32 atan2 via f64 atan2 + single rounding (verified R7/R8/R9 pass).
__device__ __forceinline__ float cr_atan2f(float y, float x) {
    return (float)atan2((double)y, (double)x);
}

__device__ __forceinline__ float clipf(float x, float lo, float hi) {
    return fminf(fmaxf(x, lo), hi);
}

struct V3 { float a, b, c; };

__device__ __forceinline__ V3 dyn(float y0, float y1, float y2, float u, float dtv) {
#pragma clang fp contract(off)
    const float PI_F = (float)3.141592653589793;
    const float TP_F = (float)6.283185307179586;   // == 2*PI_F exactly
    float th = cr_atan2f(y1, y0);
    // numpy mod(th+pi, 2pi) == (w < TP_F) ? w : 0 for w=th+PI_F in [0,TP_F]
    float w = th + PI_F;
    float r = (w < TP_F) ? w : 0.0f;
    th = r - PI_F;
    float acc = 15.0f * y1 + 3.0f * u;
    float nd  = clipf(y2 + acc * dtv, -8.0f, 8.0f);
    float nth = th + nd * dtv;
    float s, c;
    np_sincosf(nth, &s, &c);
    return V3{ -s * nd, c * nd, acc };
}

// Occupancy is grid-limited (512 waves = 2/CU); (64,1) frees the VGPR budget.
__global__ __launch_bounds__(64, 1) void pend_rollout(
        const float* __restrict__ ob,
        const float* __restrict__ acs,
        const float* __restrict__ times,
        float* __restrict__ out, int B) {
#pragma clang fp contract(off)
    int b = blockIdx.x * blockDim.x + threadIdx.x;
    if (b >= B) return;

    const float* tb = times + (size_t)b * EP;
    const float* ab = acs   + (size_t)b * EP;
    float* orow = out + (size_t)b * EP * 3;

    float y0 = ob[b * 3 + 0], y1v = ob[b * 3 + 1], y2 = ob[b * 3 + 2];
    orow[0] = y0; orow[1] = y1v; orow[2] = y2;

    const float c21 = (float)(1.0/5.0);
    const float c31 = (float)(3.0/40.0),      c32 = (float)(9.0/40.0);
    const float c41 = (float)(44.0/45.0),     c42 = (float)(56.0/15.0),    c43 = (float)(32.0/9.0);
    const float c51 = (float)(19372.0/6561.0),c52 = (float)(25360.0/2187.0),
                c53 = (float)(64448.0/6561.0),c54 = (float)(212.0/729.0);
    const float c61 = (float)(9017.0/3168.0), c62 = (float)(355.0/33.0),
                c63 = (float)(46732.0/5247.0),c64 = (float)(49.0/176.0),   c65 = (float)(5103.0/18656.0);
    const float b1  = (float)(35.0/384.0),    b3  = (float)(500.0/1113.0),
                b4  = (float)(125.0/192.0),   b5  = (float)(2187.0/6784.0),b6  = (float)(11.0/84.0);

    float t0 = tb[0];
    float t1 = tb[1];
    float a1 = ab[1];
    float u0 = clipf(ab[0], -2.0f, 2.0f);     // rolled forward each step

    for (int i = 0; i < EP - 1; ++i) {
        // prefetch next t/a early (hide under the heavy compute)
        int i2 = (i + 2 < EP) ? (i + 2) : (EP - 1);
        float t2 = tb[i2];
        float a2 = ab[i2];

        float h   = t1 - t0;
        float u1c = clipf(a1, -2.0f, 2.0f);   // == next step's u0

        // stage-6 time t0+h in f32: runtime searchsorted emulation
        float t6 = t0 + h;
        float u6, dt6;
        if (t6 >= t1) {
            u6  = u1c;
            dt6 = t2 - t1;
        } else {
            u6  = u0;
            dt6 = h;
        }

        V3 k1 = dyn(y0, y1v, y2, u0, h);

        float ta = c21 * k1.a, tb_ = c21 * k1.b, tc = c21 * k1.c;
        V3 k2 = dyn(y0 + h * ta, y1v + h * tb_, y2 + h * tc, u0, h);

        float a3  = c31 * k1.a + c32 * k2.a;
        float b3_ = c31 * k1.b + c32 * k2.b;
        float cc3 = c31 * k1.c + c32 * k2.c;
        V3 k3 = dyn(y0 + h * a3, y1v + h * b3_, y2 + h * cc3, u0, h);

        float a4  = c41 * k1.a - c42 * k2.a + c43 * k3.a;
        float b4_ = c41 * k1.b - c42 * k2.b + c43 * k3.b;
        float cc4 = c41 * k1.c - c42 * k2.c + c43 * k3.c;
        V3 k4 = dyn(y0 + h * a4, y1v + h * b4_, y2 + h * cc4, u0, h);

        float a5  = c51 * k1.a - c52 * k2.a + c53 * k3.a - c54 * k4.a;
        float b5_ = c51 * k1.b - c52 * k2.b + c53 * k3.b - c54 * k4.b;
        float cc5 = c51 * k1.c - c52 * k2.c + c53 * k3.c - c54 * k4.c;
        V3 k5 = dyn(y0 + h * a5, y1v + h * b5_, y2 + h * cc5, u0, h);

        float a6  = c61 * k1.a - c62 * k2.a + c63 * k3.a + c64 * k4.a - c65 * k5.a;
        float b6_ = c61 * k1.b - c62 * k2.b + c63 * k3.b + c64 * k4.b - c65 * k5.b;
        float cc6 = c61 * k1.c - c62 * k2.c + c63 * k3.c + c64 * k4.c - c65 * k5.c;
        V3 k6 = dyn(y0 + h * a6, y1v + h * b6_, y2 + h * cc6, u6, dt6);

        float ua = b1 * k1.a + b3 * k3.a + b4 * k4.a - b5 * k5.a + b6 * k6.a;
        float ub = b1 * k1.b + b3 * k3.b + b4 * k4.b - b5 * k5.b + b6 * k6.b;
        float uc = b1 * k1.c + b3 * k3.c + b4 * k4.c - b5 * k5.c + b6 * k6.c;
        y0  = y0  + h * ua;
        y1v = y1v + h * ub;
        y2  = y2  + h * uc;

        float* rr = orow + (size_t)(i + 1) * 3;
        rr[0] = y0; rr[1] = y1v; rr[2] = y2;

        t0 = t1; t1 = t2;
        a1 = a2;
        u0 = u1c;
    }
}

} // namespace

extern "C" void kernel_launch(void* const* d_in, const int* in_sizes, int n_in,
                              void* d_out, int out_size, void* d_ws, size_t ws_size,
                              hipStream_t stream) {
    const float* ob    = (const float*)d_in[0];
    const float* acs   = (const float*)d_in[1];
    const float* times = (const float*)d_in[2];
    float* out = (float*)d_out;
    int B = in_sizes[0] / 3;

    int block = 64;
    int grid = (B + block - 1) / block;
    pend_rollout<<<grid, block, 0, stream>>>(ob, acs, times, out, B);
}